// Round 8
// baseline (1085.027 us; speedup 1.0000x reference)
//
#include <hip/hip_runtime.h>

// Batched integer Jonker-Volgenant LAP, one wave64 per problem.
// u16-quantized costs staged in LDS (128 KB); exact integer solve on Q,
// loss evaluated on original fp32. Phases: column reduction -> greedy claim
// -> LAPJV reduction transfer -> 2x augmenting row reduction -> SAP with
// persistently-packed (val<<8|col) spc, pipelined argmin (pm carried across
// steps, recomputed in the load shadow), and SPECULATIVE next-row prefetch:
// the carried pm predicts the next visited col one iteration early; on a
// hit the next Q-row is already in registers (zero exposed LDS latency).

#define N 256
typedef unsigned int u32;

static __device__ __forceinline__ u32 umin2(u32 a, u32 b) { return a < b ? a : b; }
static __device__ __forceinline__ u32 umax2(u32 a, u32 b) { return a < b ? b : a; }

template <int CTRL, int RM>
static __device__ __forceinline__ u32 dppmin(u32 x) {
    u32 t = (u32)__builtin_amdgcn_update_dpp((int)x, (int)x, CTRL, RM, 0xF, false);
    return umin2(x, t);
}

// full-wave min of u32; returns broadcast scalar (SGPR)
static __device__ __forceinline__ u32 wave_min64(u32 x) {
    x = dppmin<0xB1, 0xF>(x);    // quad_perm xor1
    x = dppmin<0x4E, 0xF>(x);    // quad_perm xor2
    x = dppmin<0x141, 0xF>(x);   // row_half_mirror
    x = dppmin<0x140, 0xF>(x);   // row_mirror
    x = dppmin<0x142, 0xA>(x);   // bcast15
    x = dppmin<0x143, 0x8>(x);   // bcast31
    return (u32)__builtin_amdgcn_readlane((int)x, 63);
}

template <int CTRL, int RM>
static __device__ __forceinline__ void dpp2min(u32& p1, u32& p2) {
    u32 b1 = (u32)__builtin_amdgcn_update_dpp((int)p1, (int)p1, CTRL, RM, 0xF, false);
    u32 b2 = (u32)__builtin_amdgcn_update_dpp((int)p2, (int)p2, CTRL, RM, 0xF, false);
    u32 lo = umin2(p1, b1), hi = umax2(p1, b1);
    p1 = lo;
    p2 = umin2(umin2(p2, b2), hi);
}

// two smallest packed values across the wave
static __device__ __forceinline__ void wave_min2_64(u32& P1, u32& P2) {
    u32 p1 = P1, p2 = P2;
    dpp2min<0xB1, 0xF>(p1, p2);
    dpp2min<0x4E, 0xF>(p1, p2);
    dpp2min<0x141, 0xF>(p1, p2);
    dpp2min<0x140, 0xF>(p1, p2);
    dpp2min<0x142, 0xA>(p1, p2);
    dpp2min<0x143, 0x8>(p1, p2);
    P1 = (u32)__builtin_amdgcn_readlane((int)p1, 63);
    P2 = (u32)__builtin_amdgcn_readlane((int)p2, 63);
}

__global__ __launch_bounds__(64, 1) void lap_solve(const float* __restrict__ D,
                                                   float* __restrict__ partial) {
    const int b = blockIdx.x;
    const int lane = threadIdx.x;
    const int c0 = 4 * lane;
    const float* __restrict__ C = D + (size_t)b * N * N;

    __shared__ unsigned short Q[N * N];            // 128 KB quantized costs
    __shared__ int u_lds[N], col4row[N], row4col[N];
    __shared__ int path_lds[N], fA[N], fB[N], claim[N];

    // ---- phase 0: stage + quantize + column minima ----
    int v0 = 0x7fffffff, v1 = 0x7fffffff, v2 = 0x7fffffff, v3 = 0x7fffffff;
    int a0 = 0, a1 = 0, a2 = 0, a3 = 0;
    #pragma unroll 4
    for (int i = 0; i < N; ++i) {
        float4 c = *(const float4*)(C + (size_t)i * N + c0);
        int q0 = min(65535, max(0, (int)fmaf(c.x, 65536.0f, 0.5f)));
        int q1 = min(65535, max(0, (int)fmaf(c.y, 65536.0f, 0.5f)));
        int q2 = min(65535, max(0, (int)fmaf(c.z, 65536.0f, 0.5f)));
        int q3 = min(65535, max(0, (int)fmaf(c.w, 65536.0f, 0.5f)));
        *(ushort4*)(Q + i * N + c0) = make_ushort4((unsigned short)q0, (unsigned short)q1,
                                                   (unsigned short)q2, (unsigned short)q3);
        if (q0 < v0) { v0 = q0; a0 = i; }
        if (q1 < v1) { v1 = q1; a1 = i; }
        if (q2 < v2) { v2 = q2; a2 = i; }
        if (q3 < v3) { v3 = q3; a3 = i; }
    }
    for (int k = lane; k < N; k += 64) { u_lds[k] = 0; col4row[k] = -1; claim[k] = 0x7fffffff; }
    __syncthreads();

    // ---- phase 1: greedy claim on tight edges (lowest col wins a row) ----
    atomicMin(&claim[a0], c0 + 0);
    atomicMin(&claim[a1], c0 + 1);
    atomicMin(&claim[a2], c0 + 2);
    atomicMin(&claim[a3], c0 + 3);
    __syncthreads();
    int r0 = (claim[a0] == c0 + 0) ? a0 : -1; if (r0 >= 0) col4row[a0] = c0 + 0;
    int r1 = (claim[a1] == c0 + 1) ? a1 : -1; if (r1 >= 0) col4row[a1] = c0 + 1;
    int r2 = (claim[a2] == c0 + 2) ? a2 : -1; if (r2 >= 0) col4row[a2] = c0 + 2;
    int r3 = (claim[a3] == c0 + 3) ? a3 : -1; if (r3 >= 0) col4row[a3] = c0 + 3;
    row4col[c0 + 0] = r0; row4col[c0 + 1] = r1;
    row4col[c0 + 2] = r2; row4col[c0 + 3] = r3;
    __syncthreads();

    // ---- phase 1.5: LAPJV reduction transfer over greedy-assigned rows ----
    for (int i = 0; i < N; ++i) {
        int j1 = col4row[i];                       // uniform
        if (j1 < 0) continue;
        uint2 qe = *(const uint2*)(Q + i * N + c0);
        int s0 = (int)(qe.x & 0xFFFFu) - v0;
        int s1 = (int)(qe.x >> 16)     - v1;
        int s2 = (int)(qe.y & 0xFFFFu) - v2;
        int s3 = (int)(qe.y >> 16)     - v3;
        if (c0 + 0 == j1) s0 = 0x7fffffff;
        if (c0 + 1 == j1) s1 = 0x7fffffff;
        if (c0 + 2 == j1) s2 = 0x7fffffff;
        if (c0 + 3 == j1) s3 = 0x7fffffff;
        int mn = (int)wave_min64(umin2(umin2((u32)s0, (u32)s1), umin2((u32)s2, (u32)s3)));
        if (lane == (j1 >> 2)) {
            int sl = j1 & 3;
            if      (sl == 0) v0 -= mn;
            else if (sl == 1) v1 -= mn;
            else if (sl == 2) v2 -= mn;
            else              v3 -= mn;
        }
        if (lane == 0) u_lds[i] = mn;
    }
    __syncthreads();

    // ---- build free-row list (ascending) ----
    int nfree;
    {
        int4 cc = *(const int4*)&col4row[c0];
        int f0 = (cc.x < 0), f1 = (cc.y < 0), f2 = (cc.z < 0), f3 = (cc.w < 0);
        int cnt = f0 + f1 + f2 + f3;
        int inc = cnt;
        #pragma unroll
        for (int off = 1; off < 64; off <<= 1) {
            int t = __shfl_up(inc, off);
            if (lane >= off) inc += t;
        }
        int pos = inc - cnt;
        if (f0) fA[pos++] = c0 + 0;
        if (f1) fA[pos++] = c0 + 1;
        if (f2) fA[pos++] = c0 + 2;
        if (f3) fA[pos++] = c0 + 3;
        nfree = __builtin_amdgcn_readlane(inc, 63);
    }
    __syncthreads();

    // ---- phase 2: JV augmenting row reduction (2 passes) ----
    int* fcur = fA;
    int* fnxt = fB;
    for (int pass = 0; pass < 2 && nfree > 0; ++pass) {
        int k = 0, n2 = 0;
        while (k < nfree) {
            int i = fcur[k]; k++;
            uint2 qe = *(const uint2*)(Q + i * N + c0);
            u32 q0p = ((u32)((int)(qe.x & 0xFFFFu) - v0) << 8) | (u32)(c0 + 0);
            u32 q1p = ((u32)((int)(qe.x >> 16)     - v1) << 8) | (u32)(c0 + 1);
            u32 q2p = ((u32)((int)(qe.y & 0xFFFFu) - v2) << 8) | (u32)(c0 + 2);
            u32 q3p = ((u32)((int)(qe.y >> 16)     - v3) << 8) | (u32)(c0 + 3);
            u32 m01 = umin2(q0p, q1p), M01 = umax2(q0p, q1p);
            u32 m23 = umin2(q2p, q3p), M23 = umax2(q2p, q3p);
            u32 P1 = umin2(m01, m23);
            u32 P2 = umin2(umax2(m01, m23), umin2(M01, M23));
            wave_min2_64(P1, P2);
            int u1 = (int)(P1 >> 8), j1 = (int)(P1 & 255);
            int u2 = (int)(P2 >> 8), j2 = (int)(P2 & 255);
            int i0 = row4col[j1];
            if (u1 < u2) {
                int d = u2 - u1, ow = j1 >> 2, sl = j1 & 3;
                if (lane == ow) {
                    if (sl == 0) v0 -= d; else if (sl == 1) v1 -= d;
                    else if (sl == 2) v2 -= d; else v3 -= d;
                }
            } else if (i0 >= 0) {
                j1 = j2;
                i0 = row4col[j2];
            }
            if (lane == 0) { row4col[j1] = i; col4row[i] = j1; u_lds[i] = u2; }
            if (i0 >= 0) {
                if (lane == 0) col4row[i0] = -1;
                if (u1 < u2) { k--; if (lane == 0) fcur[k] = i0; }
                else         { if (lane == 0) fnxt[n2] = i0; n2++; }
            }
            __syncthreads();
        }
        int* t = fcur; fcur = fnxt; fnxt = t;
        nfree = n2;
    }

    { int4 rr = *(const int4*)&row4col[c0]; r0 = rr.x; r1 = rr.y; r2 = rr.z; r3 = rr.w; }

    // ---- phase 3: SAP, packed spc, pipelined argmin + speculative prefetch ----
    const int VISCW = 0x30000000;
    for (int fi = 0; fi < nfree; ++fi) {
        int cur = fcur[fi];
        u32 spc0 = ~0u, spc1 = ~0u, spc2 = ~0u, spc3 = ~0u;
        int pa0 = -1, pa1 = -1, pa2 = -1, pa3 = -1;
        int sv0 = 0, sv1 = 0, sv2 = 0, sv3 = 0;
        int sq0 = -1, sq1 = -1, sq2 = -1, sq3 = -1;
        int cw0 = (int)((u32)(c0 + 0) - ((u32)v0 << 8));
        int cw1 = (int)((u32)(c0 + 1) - ((u32)v1 << 8));
        int cw2 = (int)((u32)(c0 + 2) - ((u32)v2 << 8));
        int cw3 = (int)((u32)(c0 + 3) - ((u32)v3 << 8));
        int scm = 0, minVal = 0, sink;
        int i = cur;
        uint2 qrow = *(const uint2*)(Q + i * N + c0);   // prologue load
        int ui = u_lds[i];
        u32 pm = 0xFFFFFFFFu;                           // min(spc) carried across steps
        int pred_col = -1;                              // speculative state
        uint2 pq = make_uint2(0, 0);
        int pu = 0;

        for (;;) {
            // relax row i (qrow/ui ready: prefetched on hit, else issued last iter)
            u32 sbase = (u32)(minVal - ui) << 8;
            u32 n0 = sbase + ((qrow.x << 8) & 0x00FFFF00u) + (u32)cw0;
            u32 n1 = sbase + ((qrow.x >> 8) & 0x00FFFF00u) + (u32)cw1;
            u32 n2_ = sbase + ((qrow.y << 8) & 0x00FFFF00u) + (u32)cw2;
            u32 n3 = sbase + ((qrow.y >> 8) & 0x00FFFF00u) + (u32)cw3;
            if (n0 < spc0)  { spc0 = n0;  pa0 = i; }
            if (n1 < spc1)  { spc1 = n1;  pa1 = i; }
            if (n2_ < spc2) { spc2 = n2_; pa2 = i; }
            if (n3 < spc3)  { spc3 = n3;  pa3 = i; }

            // critical chain: min over NEW candidates only, merged with carried pm
            u32 c2 = wave_min64(umin2(umin2(n0, n1), umin2(n2_, n3)));
            u32 best = umin2(pm, c2);                   // SALU (both SGPR)
            int j = (int)(best & 255u);
            minVal = (int)(best >> 8);
            int sl = j & 3, ow = j >> 2;
            int rc = (sl == 0) ? r0 : (sl == 1) ? r1 : (sl == 2) ? r2 : r3;
            int rj = __builtin_amdgcn_readlane(rc, ow);

            // visit col j (also needed on the break path for path/dual updates)
            if (lane == ow) {
                scm |= (1 << sl);
                if      (sl == 0) { sv0 = minVal; sq0 = pa0; spc0 = ~0u; cw0 = VISCW; }
                else if (sl == 1) { sv1 = minVal; sq1 = pa1; spc1 = ~0u; cw1 = VISCW; }
                else if (sl == 2) { sv2 = minVal; sq2 = pa2; spc2 = ~0u; cw2 = VISCW; }
                else              { sv3 = minVal; sq3 = pa3; spc3 = ~0u; cw3 = VISCW; }
            }
            if (rj < 0) { sink = j; break; }

            // next row's data: speculative hit (loaded a full iteration ago) or
            // fallback load issued now (same point as before)
            i = rj;
            if (j == pred_col) { qrow = pq; ui = pu; }   // uniform branch
            else { qrow = *(const uint2*)(Q + i * N + c0); ui = u_lds[i]; }

            // shadow work under the load: recompute pm, predict next col,
            // speculatively load its matched row for the iteration AFTER next
            pm = wave_min64(umin2(umin2(spc0, spc1), umin2(spc2, spc3)));
            int jp = (int)(pm & 255u);
            int slp = jp & 3, owp = jp >> 2;
            int rcp = (slp == 0) ? r0 : (slp == 1) ? r1 : (slp == 2) ? r2 : r3;
            int rp = __builtin_amdgcn_readlane(rcp, owp);
            if (rp >= 0) {
                pq = *(const uint2*)(Q + rp * N + c0);
                pu = u_lds[rp];
                pred_col = jp;
            } else {
                pred_col = -1;                           // predicted col is free
            }
        }

        const int minValF = minVal;

        // predecessor paths for visited cols; register-local dual update
        *(int4*)&path_lds[c0] = make_int4((scm & 1) ? sq0 : -1, (scm & 2) ? sq1 : -1,
                                          (scm & 4) ? sq2 : -1, (scm & 8) ? sq3 : -1);
        if (scm & 1) { if (r0 >= 0) u_lds[r0] += minValF - sv0; v0 += sv0 - minValF; }
        if (scm & 2) { if (r1 >= 0) u_lds[r1] += minValF - sv1; v1 += sv1 - minValF; }
        if (scm & 4) { if (r2 >= 0) u_lds[r2] += minValF - sv2; v2 += sv2 - minValF; }
        if (scm & 8) { if (r3 >= 0) u_lds[r3] += minValF - sv3; v3 += sv3 - minValF; }
        if (lane == 0) u_lds[cur] += minValF;
        __syncthreads();

        // augment along predecessor path (lane 0)
        if (lane == 0) {
            int j = sink;
            for (;;) {
                int ii = path_lds[j];
                row4col[j] = ii;
                int jn = col4row[ii];
                col4row[ii] = j;
                if (ii == cur) break;
                j = jn;
            }
        }
        __syncthreads();
        int4 rr = *(const int4*)&row4col[c0];
        r0 = rr.x; r1 = rr.y; r2 = rr.z; r3 = rr.w;
    }

    // ---- per-sample mean of matched ORIGINAL fp32 costs ----
    __syncthreads();
    int4 cc = *(const int4*)&col4row[c0];
    float s = C[(size_t)(c0 + 0) * N + cc.x] + C[(size_t)(c0 + 1) * N + cc.y]
            + C[(size_t)(c0 + 2) * N + cc.z] + C[(size_t)(c0 + 3) * N + cc.w];
    s += __shfl_xor(s, 1);  s += __shfl_xor(s, 2);  s += __shfl_xor(s, 4);
    s += __shfl_xor(s, 8);  s += __shfl_xor(s, 16); s += __shfl_xor(s, 32);
    if (lane == 0) partial[b] = s * (1.0f / N);
}

__global__ __launch_bounds__(256, 1) void reduce_final(const float* __restrict__ partial,
                                                       float* __restrict__ out, int B) {
    const int t = threadIdx.x;
    __shared__ float rv[4];
    float s = (t < B) ? partial[t] : 0.0f;
    #pragma unroll
    for (int off = 32; off > 0; off >>= 1) s += __shfl_down(s, off);
    if ((t & 63) == 0) rv[t >> 6] = s;
    __syncthreads();
    if (t == 0) out[0] = (rv[0] + rv[1] + rv[2] + rv[3]) / (float)B;
}

extern "C" void kernel_launch(void* const* d_in, const int* in_sizes, int n_in,
                              void* d_out, int out_size, void* d_ws, size_t ws_size,
                              hipStream_t stream) {
    const float* D = (const float*)d_in[0];
    float* out = (float*)d_out;
    float* partial = (float*)d_ws;                 // B floats of scratch

    const int B = in_sizes[0] / (N * N);           // 256

    lap_solve<<<B, 64, 0, stream>>>(D, partial);
    reduce_final<<<1, 256, 0, stream>>>(partial, out, B);
}

// Round 9
// 1071.294 us; speedup vs baseline: 1.0128x; 1.0128x over previous
//
#include <hip/hip_runtime.h>

// Batched integer Jonker-Volgenant LAP, one wave64 per problem.
// u16-quantized costs staged in LDS (128 KB); exact integer solve on Q,
// loss evaluated on original fp32. Phases: column reduction -> greedy claim
// -> LAPJV reduction transfer -> 2x augmenting row reduction -> SAP with
// persistently-packed (val<<8|col) spc, pipelined argmin (pm carried in the
// load shadow), and a SCALARIZED post-argmin decode: next row via packed
// row4col bytes (readlane+bfe) and free-col test via 4x u64 scalar masks.

#define N 256
typedef unsigned int u32;
typedef unsigned long long u64;

static __device__ __forceinline__ u32 umin2(u32 a, u32 b) { return a < b ? a : b; }
static __device__ __forceinline__ u32 umax2(u32 a, u32 b) { return a < b ? b : a; }

template <int CTRL, int RM>
static __device__ __forceinline__ u32 dppmin(u32 x) {
    u32 t = (u32)__builtin_amdgcn_update_dpp((int)x, (int)x, CTRL, RM, 0xF, false);
    return umin2(x, t);
}

// full-wave min of u32; returns broadcast scalar (SGPR)
static __device__ __forceinline__ u32 wave_min64(u32 x) {
    x = dppmin<0xB1, 0xF>(x);    // quad_perm xor1
    x = dppmin<0x4E, 0xF>(x);    // quad_perm xor2
    x = dppmin<0x141, 0xF>(x);   // row_half_mirror
    x = dppmin<0x140, 0xF>(x);   // row_mirror
    x = dppmin<0x142, 0xA>(x);   // bcast15
    x = dppmin<0x143, 0x8>(x);   // bcast31
    return (u32)__builtin_amdgcn_readlane((int)x, 63);
}

template <int CTRL, int RM>
static __device__ __forceinline__ void dpp2min(u32& p1, u32& p2) {
    u32 b1 = (u32)__builtin_amdgcn_update_dpp((int)p1, (int)p1, CTRL, RM, 0xF, false);
    u32 b2 = (u32)__builtin_amdgcn_update_dpp((int)p2, (int)p2, CTRL, RM, 0xF, false);
    u32 lo = umin2(p1, b1), hi = umax2(p1, b1);
    p1 = lo;
    p2 = umin2(umin2(p2, b2), hi);
}

// two smallest packed values across the wave
static __device__ __forceinline__ void wave_min2_64(u32& P1, u32& P2) {
    u32 p1 = P1, p2 = P2;
    dpp2min<0xB1, 0xF>(p1, p2);
    dpp2min<0x4E, 0xF>(p1, p2);
    dpp2min<0x141, 0xF>(p1, p2);
    dpp2min<0x140, 0xF>(p1, p2);
    dpp2min<0x142, 0xA>(p1, p2);
    dpp2min<0x143, 0x8>(p1, p2);
    P1 = (u32)__builtin_amdgcn_readlane((int)p1, 63);
    P2 = (u32)__builtin_amdgcn_readlane((int)p2, 63);
}

__global__ __launch_bounds__(64, 1) void lap_solve(const float* __restrict__ D,
                                                   float* __restrict__ partial) {
    const int b = blockIdx.x;
    const int lane = threadIdx.x;
    const int c0 = 4 * lane;
    const float* __restrict__ C = D + (size_t)b * N * N;

    __shared__ unsigned short Q[N * N];            // 128 KB quantized costs
    __shared__ int u_lds[N], col4row[N], row4col[N];
    __shared__ int path_lds[N], fA[N], fB[N], claim[N];

    // ---- phase 0: stage + quantize + column minima ----
    int v0 = 0x7fffffff, v1 = 0x7fffffff, v2 = 0x7fffffff, v3 = 0x7fffffff;
    int a0 = 0, a1 = 0, a2 = 0, a3 = 0;
    #pragma unroll 4
    for (int i = 0; i < N; ++i) {
        float4 c = *(const float4*)(C + (size_t)i * N + c0);
        int q0 = min(65535, max(0, (int)fmaf(c.x, 65536.0f, 0.5f)));
        int q1 = min(65535, max(0, (int)fmaf(c.y, 65536.0f, 0.5f)));
        int q2 = min(65535, max(0, (int)fmaf(c.z, 65536.0f, 0.5f)));
        int q3 = min(65535, max(0, (int)fmaf(c.w, 65536.0f, 0.5f)));
        *(ushort4*)(Q + i * N + c0) = make_ushort4((unsigned short)q0, (unsigned short)q1,
                                                   (unsigned short)q2, (unsigned short)q3);
        if (q0 < v0) { v0 = q0; a0 = i; }
        if (q1 < v1) { v1 = q1; a1 = i; }
        if (q2 < v2) { v2 = q2; a2 = i; }
        if (q3 < v3) { v3 = q3; a3 = i; }
    }
    for (int k = lane; k < N; k += 64) { u_lds[k] = 0; col4row[k] = -1; claim[k] = 0x7fffffff; }
    __syncthreads();

    // ---- phase 1: greedy claim on tight edges (lowest col wins a row) ----
    atomicMin(&claim[a0], c0 + 0);
    atomicMin(&claim[a1], c0 + 1);
    atomicMin(&claim[a2], c0 + 2);
    atomicMin(&claim[a3], c0 + 3);
    __syncthreads();
    int r0 = (claim[a0] == c0 + 0) ? a0 : -1; if (r0 >= 0) col4row[a0] = c0 + 0;
    int r1 = (claim[a1] == c0 + 1) ? a1 : -1; if (r1 >= 0) col4row[a1] = c0 + 1;
    int r2 = (claim[a2] == c0 + 2) ? a2 : -1; if (r2 >= 0) col4row[a2] = c0 + 2;
    int r3 = (claim[a3] == c0 + 3) ? a3 : -1; if (r3 >= 0) col4row[a3] = c0 + 3;
    row4col[c0 + 0] = r0; row4col[c0 + 1] = r1;
    row4col[c0 + 2] = r2; row4col[c0 + 3] = r3;
    __syncthreads();

    // ---- phase 1.5: LAPJV reduction transfer over greedy-assigned rows ----
    for (int i = 0; i < N; ++i) {
        int j1 = col4row[i];                       // uniform
        if (j1 < 0) continue;
        uint2 qe = *(const uint2*)(Q + i * N + c0);
        int s0 = (int)(qe.x & 0xFFFFu) - v0;
        int s1 = (int)(qe.x >> 16)     - v1;
        int s2 = (int)(qe.y & 0xFFFFu) - v2;
        int s3 = (int)(qe.y >> 16)     - v3;
        if (c0 + 0 == j1) s0 = 0x7fffffff;
        if (c0 + 1 == j1) s1 = 0x7fffffff;
        if (c0 + 2 == j1) s2 = 0x7fffffff;
        if (c0 + 3 == j1) s3 = 0x7fffffff;
        int mn = (int)wave_min64(umin2(umin2((u32)s0, (u32)s1), umin2((u32)s2, (u32)s3)));
        if (lane == (j1 >> 2)) {
            int sl = j1 & 3;
            if      (sl == 0) v0 -= mn;
            else if (sl == 1) v1 -= mn;
            else if (sl == 2) v2 -= mn;
            else              v3 -= mn;
        }
        if (lane == 0) u_lds[i] = mn;
    }
    __syncthreads();

    // ---- build free-row list (ascending) ----
    int nfree;
    {
        int4 cc = *(const int4*)&col4row[c0];
        int f0 = (cc.x < 0), f1 = (cc.y < 0), f2 = (cc.z < 0), f3 = (cc.w < 0);
        int cnt = f0 + f1 + f2 + f3;
        int inc = cnt;
        #pragma unroll
        for (int off = 1; off < 64; off <<= 1) {
            int t = __shfl_up(inc, off);
            if (lane >= off) inc += t;
        }
        int pos = inc - cnt;
        if (f0) fA[pos++] = c0 + 0;
        if (f1) fA[pos++] = c0 + 1;
        if (f2) fA[pos++] = c0 + 2;
        if (f3) fA[pos++] = c0 + 3;
        nfree = __builtin_amdgcn_readlane(inc, 63);
    }
    __syncthreads();

    // ---- phase 2: JV augmenting row reduction (2 passes) ----
    int* fcur = fA;
    int* fnxt = fB;
    for (int pass = 0; pass < 2 && nfree > 0; ++pass) {
        int k = 0, n2 = 0;
        while (k < nfree) {
            int i = fcur[k]; k++;
            uint2 qe = *(const uint2*)(Q + i * N + c0);
            u32 q0p = ((u32)((int)(qe.x & 0xFFFFu) - v0) << 8) | (u32)(c0 + 0);
            u32 q1p = ((u32)((int)(qe.x >> 16)     - v1) << 8) | (u32)(c0 + 1);
            u32 q2p = ((u32)((int)(qe.y & 0xFFFFu) - v2) << 8) | (u32)(c0 + 2);
            u32 q3p = ((u32)((int)(qe.y >> 16)     - v3) << 8) | (u32)(c0 + 3);
            u32 m01 = umin2(q0p, q1p), M01 = umax2(q0p, q1p);
            u32 m23 = umin2(q2p, q3p), M23 = umax2(q2p, q3p);
            u32 P1 = umin2(m01, m23);
            u32 P2 = umin2(umax2(m01, m23), umin2(M01, M23));
            wave_min2_64(P1, P2);
            int u1 = (int)(P1 >> 8), j1 = (int)(P1 & 255);
            int u2 = (int)(P2 >> 8), j2 = (int)(P2 & 255);
            int i0 = row4col[j1];
            if (u1 < u2) {
                int d = u2 - u1, ow = j1 >> 2, sl = j1 & 3;
                if (lane == ow) {
                    if (sl == 0) v0 -= d; else if (sl == 1) v1 -= d;
                    else if (sl == 2) v2 -= d; else v3 -= d;
                }
            } else if (i0 >= 0) {
                j1 = j2;
                i0 = row4col[j2];
            }
            if (lane == 0) { row4col[j1] = i; col4row[i] = j1; u_lds[i] = u2; }
            if (i0 >= 0) {
                if (lane == 0) col4row[i0] = -1;
                if (u1 < u2) { k--; if (lane == 0) fcur[k] = i0; }
                else         { if (lane == 0) fnxt[n2] = i0; n2++; }
            }
            __syncthreads();
        }
        int* t = fcur; fcur = fnxt; fnxt = t;
        nfree = n2;
    }

    // register copies + packed row4col bytes + scalar free-col masks
    u32 rpack;
    u64 fm0, fm1, fm2, fm3;
    {
        int4 rr = *(const int4*)&row4col[c0];
        r0 = rr.x; r1 = rr.y; r2 = rr.z; r3 = rr.w;
        rpack = (u32)(r0 & 255) | ((u32)(r1 & 255) << 8)
              | ((u32)(r2 & 255) << 16) | ((u32)(r3 & 255) << 24);
        fm0 = __ballot(r0 < 0); fm1 = __ballot(r1 < 0);
        fm2 = __ballot(r2 < 0); fm3 = __ballot(r3 < 0);
    }

    // ---- phase 3: SAP, packed spc, pipelined argmin, scalar decode ----
    const int VISCW = 0x30000000;
    for (int fi = 0; fi < nfree; ++fi) {
        int cur = fcur[fi];
        u32 spc0 = ~0u, spc1 = ~0u, spc2 = ~0u, spc3 = ~0u;
        int pa0 = -1, pa1 = -1, pa2 = -1, pa3 = -1;
        int sv0 = 0, sv1 = 0, sv2 = 0, sv3 = 0;
        int sq0 = -1, sq1 = -1, sq2 = -1, sq3 = -1;
        int cw0 = (int)((u32)(c0 + 0) - ((u32)v0 << 8));
        int cw1 = (int)((u32)(c0 + 1) - ((u32)v1 << 8));
        int cw2 = (int)((u32)(c0 + 2) - ((u32)v2 << 8));
        int cw3 = (int)((u32)(c0 + 3) - ((u32)v3 << 8));
        int scm = 0, minVal = 0, sink;
        int i = cur;
        uint2 qrow = *(const uint2*)(Q + i * N + c0);   // prologue load
        int ui = u_lds[i];
        u32 pm = 0xFFFFFFFFu;                           // min(spc) carried across steps

        for (;;) {
            // relax row i (qrow/ui issued at end of previous iteration)
            u32 sbase = (u32)(minVal - ui) << 8;
            u32 n0 = sbase + ((qrow.x << 8) & 0x00FFFF00u) + (u32)cw0;
            u32 n1 = sbase + ((qrow.x >> 8) & 0x00FFFF00u) + (u32)cw1;
            u32 n2_ = sbase + ((qrow.y << 8) & 0x00FFFF00u) + (u32)cw2;
            u32 n3 = sbase + ((qrow.y >> 8) & 0x00FFFF00u) + (u32)cw3;
            if (n0 < spc0)  { spc0 = n0;  pa0 = i; }
            if (n1 < spc1)  { spc1 = n1;  pa1 = i; }
            if (n2_ < spc2) { spc2 = n2_; pa2 = i; }
            if (n3 < spc3)  { spc3 = n3;  pa3 = i; }

            // critical chain: min over NEW candidates only, merged with carried pm
            u32 c2 = wave_min64(umin2(umin2(n0, n1), umin2(n2_, n3)));
            u32 best = umin2(pm, c2);                   // SALU (both SGPR)
            int j = (int)(best & 255u);
            minVal = (int)(best >> 8);
            int sl = j & 3, ow = j >> 2;

            // visit col j (also needed on the break path for path/dual updates)
            if (lane == ow) {
                scm |= (1 << sl);
                if      (sl == 0) { sv0 = minVal; sq0 = pa0; spc0 = ~0u; cw0 = VISCW; }
                else if (sl == 1) { sv1 = minVal; sq1 = pa1; spc1 = ~0u; cw1 = VISCW; }
                else if (sl == 2) { sv2 = minVal; sq2 = pa2; spc2 = ~0u; cw2 = VISCW; }
                else              { sv3 = minVal; sq3 = pa3; spc3 = ~0u; cw3 = VISCW; }
            }

            // free-col test: pure scalar (no VGPR select, no readlane on this path)
            u64 fmsel = (sl == 0) ? fm0 : (sl == 1) ? fm1 : (sl == 2) ? fm2 : fm3;
            if ((fmsel >> ow) & 1ull) { sink = j; break; }

            // matched: next row from packed row4col bytes (readlane + byte extract)
            i = (__builtin_amdgcn_readlane((int)rpack, ow) >> (sl * 8)) & 255;
            qrow = *(const uint2*)(Q + i * N + c0);
            ui = u_lds[i];
            pm = wave_min64(umin2(umin2(spc0, spc1), umin2(spc2, spc3)));
        }

        const int minValF = minVal;

        // predecessor paths for visited cols; register-local dual update
        *(int4*)&path_lds[c0] = make_int4((scm & 1) ? sq0 : -1, (scm & 2) ? sq1 : -1,
                                          (scm & 4) ? sq2 : -1, (scm & 8) ? sq3 : -1);
        if (scm & 1) { if (r0 >= 0) u_lds[r0] += minValF - sv0; v0 += sv0 - minValF; }
        if (scm & 2) { if (r1 >= 0) u_lds[r1] += minValF - sv1; v1 += sv1 - minValF; }
        if (scm & 4) { if (r2 >= 0) u_lds[r2] += minValF - sv2; v2 += sv2 - minValF; }
        if (scm & 8) { if (r3 >= 0) u_lds[r3] += minValF - sv3; v3 += sv3 - minValF; }
        if (lane == 0) u_lds[cur] += minValF;
        __syncthreads();

        // augment along predecessor path (lane 0)
        if (lane == 0) {
            int j = sink;
            for (;;) {
                int ii = path_lds[j];
                row4col[j] = ii;
                int jn = col4row[ii];
                col4row[ii] = j;
                if (ii == cur) break;
                j = jn;
            }
        }
        __syncthreads();
        int4 rr = *(const int4*)&row4col[c0];
        r0 = rr.x; r1 = rr.y; r2 = rr.z; r3 = rr.w;
        rpack = (u32)(r0 & 255) | ((u32)(r1 & 255) << 8)
              | ((u32)(r2 & 255) << 16) | ((u32)(r3 & 255) << 24);
        fm0 = __ballot(r0 < 0); fm1 = __ballot(r1 < 0);
        fm2 = __ballot(r2 < 0); fm3 = __ballot(r3 < 0);
    }

    // ---- per-sample mean of matched ORIGINAL fp32 costs ----
    __syncthreads();
    int4 cc = *(const int4*)&col4row[c0];
    float s = C[(size_t)(c0 + 0) * N + cc.x] + C[(size_t)(c0 + 1) * N + cc.y]
            + C[(size_t)(c0 + 2) * N + cc.z] + C[(size_t)(c0 + 3) * N + cc.w];
    s += __shfl_xor(s, 1);  s += __shfl_xor(s, 2);  s += __shfl_xor(s, 4);
    s += __shfl_xor(s, 8);  s += __shfl_xor(s, 16); s += __shfl_xor(s, 32);
    if (lane == 0) partial[b] = s * (1.0f / N);
}

__global__ __launch_bounds__(256, 1) void reduce_final(const float* __restrict__ partial,
                                                       float* __restrict__ out, int B) {
    const int t = threadIdx.x;
    __shared__ float rv[4];
    float s = (t < B) ? partial[t] : 0.0f;
    #pragma unroll
    for (int off = 32; off > 0; off >>= 1) s += __shfl_down(s, off);
    if ((t & 63) == 0) rv[t >> 6] = s;
    __syncthreads();
    if (t == 0) out[0] = (rv[0] + rv[1] + rv[2] + rv[3]) / (float)B;
}

extern "C" void kernel_launch(void* const* d_in, const int* in_sizes, int n_in,
                              void* d_out, int out_size, void* d_ws, size_t ws_size,
                              hipStream_t stream) {
    const float* D = (const float*)d_in[0];
    float* out = (float*)d_out;
    float* partial = (float*)d_ws;                 // B floats of scratch

    const int B = in_sizes[0] / (N * N);           // 256

    lap_solve<<<B, 64, 0, stream>>>(D, partial);
    reduce_final<<<1, 256, 0, stream>>>(partial, out, B);
}

// Round 10
// 1043.080 us; speedup vs baseline: 1.0402x; 1.0270x over previous
//
#include <hip/hip_runtime.h>

// Batched integer Jonker-Volgenant LAP, one wave64 per problem.
// u16-quantized costs staged in LDS (128 KB); exact integer solve on Q,
// loss evaluated on original fp32. Phases: column reduction -> greedy claim
// -> LAPJV reduction transfer -> 2x augmenting row reduction -> SAP with
// persistently-packed (val<<8|col) spc and a PIPELINED wave argmin:
// best = min(pm_carried, min(new_candidates)); the recompute of pm for the
// next step runs while the next row's ds_read is in flight.
// [R10 = exact revert to the best-measured R6 kernel: R4/R7/R8/R9's
//  speculative/scalarized variants all regressed on this serial chain.]

#define N 256
typedef unsigned int u32;

static __device__ __forceinline__ u32 umin2(u32 a, u32 b) { return a < b ? a : b; }
static __device__ __forceinline__ u32 umax2(u32 a, u32 b) { return a < b ? b : a; }

template <int CTRL, int RM>
static __device__ __forceinline__ u32 dppmin(u32 x) {
    u32 t = (u32)__builtin_amdgcn_update_dpp((int)x, (int)x, CTRL, RM, 0xF, false);
    return umin2(x, t);
}

// full-wave min of u32; returns broadcast scalar (SGPR)
static __device__ __forceinline__ u32 wave_min64(u32 x) {
    x = dppmin<0xB1, 0xF>(x);    // quad_perm xor1
    x = dppmin<0x4E, 0xF>(x);    // quad_perm xor2
    x = dppmin<0x141, 0xF>(x);   // row_half_mirror
    x = dppmin<0x140, 0xF>(x);   // row_mirror
    x = dppmin<0x142, 0xA>(x);   // bcast15
    x = dppmin<0x143, 0x8>(x);   // bcast31
    return (u32)__builtin_amdgcn_readlane((int)x, 63);
}

template <int CTRL, int RM>
static __device__ __forceinline__ void dpp2min(u32& p1, u32& p2) {
    u32 b1 = (u32)__builtin_amdgcn_update_dpp((int)p1, (int)p1, CTRL, RM, 0xF, false);
    u32 b2 = (u32)__builtin_amdgcn_update_dpp((int)p2, (int)p2, CTRL, RM, 0xF, false);
    u32 lo = umin2(p1, b1), hi = umax2(p1, b1);
    p1 = lo;
    p2 = umin2(umin2(p2, b2), hi);
}

// two smallest packed values across the wave
static __device__ __forceinline__ void wave_min2_64(u32& P1, u32& P2) {
    u32 p1 = P1, p2 = P2;
    dpp2min<0xB1, 0xF>(p1, p2);
    dpp2min<0x4E, 0xF>(p1, p2);
    dpp2min<0x141, 0xF>(p1, p2);
    dpp2min<0x140, 0xF>(p1, p2);
    dpp2min<0x142, 0xA>(p1, p2);
    dpp2min<0x143, 0x8>(p1, p2);
    P1 = (u32)__builtin_amdgcn_readlane((int)p1, 63);
    P2 = (u32)__builtin_amdgcn_readlane((int)p2, 63);
}

__global__ __launch_bounds__(64, 1) void lap_solve(const float* __restrict__ D,
                                                   float* __restrict__ partial) {
    const int b = blockIdx.x;
    const int lane = threadIdx.x;
    const int c0 = 4 * lane;
    const float* __restrict__ C = D + (size_t)b * N * N;

    __shared__ unsigned short Q[N * N];            // 128 KB quantized costs
    __shared__ int u_lds[N], col4row[N], row4col[N];
    __shared__ int path_lds[N], fA[N], fB[N], claim[N];

    // ---- phase 0: stage + quantize + column minima ----
    int v0 = 0x7fffffff, v1 = 0x7fffffff, v2 = 0x7fffffff, v3 = 0x7fffffff;
    int a0 = 0, a1 = 0, a2 = 0, a3 = 0;
    #pragma unroll 4
    for (int i = 0; i < N; ++i) {
        float4 c = *(const float4*)(C + (size_t)i * N + c0);
        int q0 = min(65535, max(0, (int)fmaf(c.x, 65536.0f, 0.5f)));
        int q1 = min(65535, max(0, (int)fmaf(c.y, 65536.0f, 0.5f)));
        int q2 = min(65535, max(0, (int)fmaf(c.z, 65536.0f, 0.5f)));
        int q3 = min(65535, max(0, (int)fmaf(c.w, 65536.0f, 0.5f)));
        *(ushort4*)(Q + i * N + c0) = make_ushort4((unsigned short)q0, (unsigned short)q1,
                                                   (unsigned short)q2, (unsigned short)q3);
        if (q0 < v0) { v0 = q0; a0 = i; }
        if (q1 < v1) { v1 = q1; a1 = i; }
        if (q2 < v2) { v2 = q2; a2 = i; }
        if (q3 < v3) { v3 = q3; a3 = i; }
    }
    for (int k = lane; k < N; k += 64) { u_lds[k] = 0; col4row[k] = -1; claim[k] = 0x7fffffff; }
    __syncthreads();

    // ---- phase 1: greedy claim on tight edges (lowest col wins a row) ----
    atomicMin(&claim[a0], c0 + 0);
    atomicMin(&claim[a1], c0 + 1);
    atomicMin(&claim[a2], c0 + 2);
    atomicMin(&claim[a3], c0 + 3);
    __syncthreads();
    int r0 = (claim[a0] == c0 + 0) ? a0 : -1; if (r0 >= 0) col4row[a0] = c0 + 0;
    int r1 = (claim[a1] == c0 + 1) ? a1 : -1; if (r1 >= 0) col4row[a1] = c0 + 1;
    int r2 = (claim[a2] == c0 + 2) ? a2 : -1; if (r2 >= 0) col4row[a2] = c0 + 2;
    int r3 = (claim[a3] == c0 + 3) ? a3 : -1; if (r3 >= 0) col4row[a3] = c0 + 3;
    row4col[c0 + 0] = r0; row4col[c0 + 1] = r1;
    row4col[c0 + 2] = r2; row4col[c0 + 3] = r3;
    __syncthreads();

    // ---- phase 1.5: LAPJV reduction transfer over greedy-assigned rows ----
    for (int i = 0; i < N; ++i) {
        int j1 = col4row[i];                       // uniform
        if (j1 < 0) continue;
        uint2 qe = *(const uint2*)(Q + i * N + c0);
        int s0 = (int)(qe.x & 0xFFFFu) - v0;
        int s1 = (int)(qe.x >> 16)     - v1;
        int s2 = (int)(qe.y & 0xFFFFu) - v2;
        int s3 = (int)(qe.y >> 16)     - v3;
        if (c0 + 0 == j1) s0 = 0x7fffffff;
        if (c0 + 1 == j1) s1 = 0x7fffffff;
        if (c0 + 2 == j1) s2 = 0x7fffffff;
        if (c0 + 3 == j1) s3 = 0x7fffffff;
        int mn = (int)wave_min64(umin2(umin2((u32)s0, (u32)s1), umin2((u32)s2, (u32)s3)));
        if (lane == (j1 >> 2)) {
            int sl = j1 & 3;
            if      (sl == 0) v0 -= mn;
            else if (sl == 1) v1 -= mn;
            else if (sl == 2) v2 -= mn;
            else              v3 -= mn;
        }
        if (lane == 0) u_lds[i] = mn;
    }
    __syncthreads();

    // ---- build free-row list (ascending) ----
    int nfree;
    {
        int4 cc = *(const int4*)&col4row[c0];
        int f0 = (cc.x < 0), f1 = (cc.y < 0), f2 = (cc.z < 0), f3 = (cc.w < 0);
        int cnt = f0 + f1 + f2 + f3;
        int inc = cnt;
        #pragma unroll
        for (int off = 1; off < 64; off <<= 1) {
            int t = __shfl_up(inc, off);
            if (lane >= off) inc += t;
        }
        int pos = inc - cnt;
        if (f0) fA[pos++] = c0 + 0;
        if (f1) fA[pos++] = c0 + 1;
        if (f2) fA[pos++] = c0 + 2;
        if (f3) fA[pos++] = c0 + 3;
        nfree = __builtin_amdgcn_readlane(inc, 63);
    }
    __syncthreads();

    // ---- phase 2: JV augmenting row reduction (2 passes) ----
    int* fcur = fA;
    int* fnxt = fB;
    for (int pass = 0; pass < 2 && nfree > 0; ++pass) {
        int k = 0, n2 = 0;
        while (k < nfree) {
            int i = fcur[k]; k++;
            uint2 qe = *(const uint2*)(Q + i * N + c0);
            u32 q0p = ((u32)((int)(qe.x & 0xFFFFu) - v0) << 8) | (u32)(c0 + 0);
            u32 q1p = ((u32)((int)(qe.x >> 16)     - v1) << 8) | (u32)(c0 + 1);
            u32 q2p = ((u32)((int)(qe.y & 0xFFFFu) - v2) << 8) | (u32)(c0 + 2);
            u32 q3p = ((u32)((int)(qe.y >> 16)     - v3) << 8) | (u32)(c0 + 3);
            u32 m01 = umin2(q0p, q1p), M01 = umax2(q0p, q1p);
            u32 m23 = umin2(q2p, q3p), M23 = umax2(q2p, q3p);
            u32 P1 = umin2(m01, m23);
            u32 P2 = umin2(umax2(m01, m23), umin2(M01, M23));
            wave_min2_64(P1, P2);
            int u1 = (int)(P1 >> 8), j1 = (int)(P1 & 255);
            int u2 = (int)(P2 >> 8), j2 = (int)(P2 & 255);
            int i0 = row4col[j1];
            if (u1 < u2) {
                int d = u2 - u1, ow = j1 >> 2, sl = j1 & 3;
                if (lane == ow) {
                    if (sl == 0) v0 -= d; else if (sl == 1) v1 -= d;
                    else if (sl == 2) v2 -= d; else v3 -= d;
                }
            } else if (i0 >= 0) {
                j1 = j2;
                i0 = row4col[j2];
            }
            if (lane == 0) { row4col[j1] = i; col4row[i] = j1; u_lds[i] = u2; }
            if (i0 >= 0) {
                if (lane == 0) col4row[i0] = -1;
                if (u1 < u2) { k--; if (lane == 0) fcur[k] = i0; }
                else         { if (lane == 0) fnxt[n2] = i0; n2++; }
            }
            __syncthreads();
        }
        int* t = fcur; fcur = fnxt; fnxt = t;
        nfree = n2;
    }

    { int4 rr = *(const int4*)&row4col[c0]; r0 = rr.x; r1 = rr.y; r2 = rr.z; r3 = rr.w; }

    // ---- phase 3: SAP, packed spc, pipelined argmin ----
    const int VISCW = 0x30000000;
    for (int fi = 0; fi < nfree; ++fi) {
        int cur = fcur[fi];
        u32 spc0 = ~0u, spc1 = ~0u, spc2 = ~0u, spc3 = ~0u;
        int pa0 = -1, pa1 = -1, pa2 = -1, pa3 = -1;
        int sv0 = 0, sv1 = 0, sv2 = 0, sv3 = 0;
        int sq0 = -1, sq1 = -1, sq2 = -1, sq3 = -1;
        int cw0 = (int)((u32)(c0 + 0) - ((u32)v0 << 8));
        int cw1 = (int)((u32)(c0 + 1) - ((u32)v1 << 8));
        int cw2 = (int)((u32)(c0 + 2) - ((u32)v2 << 8));
        int cw3 = (int)((u32)(c0 + 3) - ((u32)v3 << 8));
        int scm = 0, minVal = 0, sink;
        int i = cur;
        uint2 qrow = *(const uint2*)(Q + i * N + c0);   // prologue load
        int ui = u_lds[i];
        u32 pm = 0xFFFFFFFFu;                           // min(spc) carried across steps

        for (;;) {
            // relax row i (qrow/ui already in flight from previous iteration)
            u32 sbase = (u32)(minVal - ui) << 8;
            u32 n0 = sbase + ((qrow.x << 8) & 0x00FFFF00u) + (u32)cw0;
            u32 n1 = sbase + ((qrow.x >> 8) & 0x00FFFF00u) + (u32)cw1;
            u32 n2_ = sbase + ((qrow.y << 8) & 0x00FFFF00u) + (u32)cw2;
            u32 n3 = sbase + ((qrow.y >> 8) & 0x00FFFF00u) + (u32)cw3;
            if (n0 < spc0)  { spc0 = n0;  pa0 = i; }
            if (n1 < spc1)  { spc1 = n1;  pa1 = i; }
            if (n2_ < spc2) { spc2 = n2_; pa2 = i; }
            if (n3 < spc3)  { spc3 = n3;  pa3 = i; }

            // critical chain: min over NEW candidates only, merged with carried pm
            u32 c2 = wave_min64(umin2(umin2(n0, n1), umin2(n2_, n3)));
            u32 best = umin2(pm, c2);                   // SALU (both SGPR)
            int j = (int)(best & 255u);
            minVal = (int)(best >> 8);
            int sl = j & 3, ow = j >> 2;
            int rc = (sl == 0) ? r0 : (sl == 1) ? r1 : (sl == 2) ? r2 : r3;
            int rj = __builtin_amdgcn_readlane(rc, ow);

            // visit col j (also needed on the break path for path/dual updates)
            if (lane == ow) {
                scm |= (1 << sl);
                if      (sl == 0) { sv0 = minVal; sq0 = pa0; spc0 = ~0u; cw0 = VISCW; }
                else if (sl == 1) { sv1 = minVal; sq1 = pa1; spc1 = ~0u; cw1 = VISCW; }
                else if (sl == 2) { sv2 = minVal; sq2 = pa2; spc2 = ~0u; cw2 = VISCW; }
                else              { sv3 = minVal; sq3 = pa3; spc3 = ~0u; cw3 = VISCW; }
            }
            if (rj < 0) { sink = j; break; }

            // issue next row's loads NOW; pm recompute overlaps their latency
            i = rj;
            qrow = *(const uint2*)(Q + i * N + c0);
            ui = u_lds[i];
            pm = wave_min64(umin2(umin2(spc0, spc1), umin2(spc2, spc3)));
        }

        const int minValF = minVal;

        // predecessor paths for visited cols; register-local dual update
        *(int4*)&path_lds[c0] = make_int4((scm & 1) ? sq0 : -1, (scm & 2) ? sq1 : -1,
                                          (scm & 4) ? sq2 : -1, (scm & 8) ? sq3 : -1);
        if (scm & 1) { if (r0 >= 0) u_lds[r0] += minValF - sv0; v0 += sv0 - minValF; }
        if (scm & 2) { if (r1 >= 0) u_lds[r1] += minValF - sv1; v1 += sv1 - minValF; }
        if (scm & 4) { if (r2 >= 0) u_lds[r2] += minValF - sv2; v2 += sv2 - minValF; }
        if (scm & 8) { if (r3 >= 0) u_lds[r3] += minValF - sv3; v3 += sv3 - minValF; }
        if (lane == 0) u_lds[cur] += minValF;
        __syncthreads();

        // augment along predecessor path (lane 0)
        if (lane == 0) {
            int j = sink;
            for (;;) {
                int ii = path_lds[j];
                row4col[j] = ii;
                int jn = col4row[ii];
                col4row[ii] = j;
                if (ii == cur) break;
                j = jn;
            }
        }
        __syncthreads();
        int4 rr = *(const int4*)&row4col[c0];
        r0 = rr.x; r1 = rr.y; r2 = rr.z; r3 = rr.w;
    }

    // ---- per-sample mean of matched ORIGINAL fp32 costs ----
    __syncthreads();
    int4 cc = *(const int4*)&col4row[c0];
    float s = C[(size_t)(c0 + 0) * N + cc.x] + C[(size_t)(c0 + 1) * N + cc.y]
            + C[(size_t)(c0 + 2) * N + cc.z] + C[(size_t)(c0 + 3) * N + cc.w];
    s += __shfl_xor(s, 1);  s += __shfl_xor(s, 2);  s += __shfl_xor(s, 4);
    s += __shfl_xor(s, 8);  s += __shfl_xor(s, 16); s += __shfl_xor(s, 32);
    if (lane == 0) partial[b] = s * (1.0f / N);
}

__global__ __launch_bounds__(256, 1) void reduce_final(const float* __restrict__ partial,
                                                       float* __restrict__ out, int B) {
    const int t = threadIdx.x;
    __shared__ float rv[4];
    float s = (t < B) ? partial[t] : 0.0f;
    #pragma unroll
    for (int off = 32; off > 0; off >>= 1) s += __shfl_down(s, off);
    if ((t & 63) == 0) rv[t >> 6] = s;
    __syncthreads();
    if (t == 0) out[0] = (rv[0] + rv[1] + rv[2] + rv[3]) / (float)B;
}

extern "C" void kernel_launch(void* const* d_in, const int* in_sizes, int n_in,
                              void* d_out, int out_size, void* d_ws, size_t ws_size,
                              hipStream_t stream) {
    const float* D = (const float*)d_in[0];
    float* out = (float*)d_out;
    float* partial = (float*)d_ws;                 // B floats of scratch

    const int B = in_sizes[0] / (N * N);           // 256

    lap_solve<<<B, 64, 0, stream>>>(D, partial);
    reduce_final<<<1, 256, 0, stream>>>(partial, out, B);
}